// Round 3
// baseline (707.340 us; speedup 1.0000x reference)
//
#include <hip/hip_runtime.h>

#define DXYZ 128
#define NVERT (DXYZ * DXYZ * DXYZ)     // 2097152 voxels per (cloud,batch) grid
#define BIN 16                          // region/bin edge in voxels
#define SBINS 512                       // spatial bins per grid (8^3)
#define CHUNK 2048                      // points per hist/scatter block

// ---------------- Pass 1: per-chunk LDS histogram (no global atomics) -------
// bcnt layout: [chunk_global][gkey]  (coalesced writes and reads everywhere)
__global__ __launch_bounds__(256) void hist2_kernel(
    const float* __restrict__ p0, const float* __restrict__ p1,
    unsigned* __restrict__ bcnt,
    int N, int B, int nchunks, int nkeys, int dup)
{
    __shared__ unsigned h[SBINS];
    for (int i = threadIdx.x; i < SBINS; i += 256) h[i] = 0u;
    __syncthreads();

    int blk = blockIdx.x;
    int cb = blk / nchunks;            // cloud*B + batch
    int c  = blk - cb * nchunks;       // chunk within slice
    const float* p = (cb < B ? p0 : p1) +
                     ((size_t)(cb % B) * N + (size_t)c * CHUNK) * 3;

    for (int i = threadIdx.x; i < CHUNK; i += 256) {
        float px = p[3*i+0] * 64.0f;
        float py = p[3*i+1] * 64.0f;
        float pz = p[3*i+2] * 64.0f;
        int ix = (int)floorf(px) + 64;
        int iy = (int)floorf(py) + 64;
        int iz = (int)floorf(pz) + 64;
        int bx0 = ix >> 4, by0 = iy >> 4, bz0 = iz >> 4;
        int bx1 = (ix+1) >> 4, by1 = (iy+1) >> 4, bz1 = (iz+1) >> 4;
        if (!dup) { bx1 = bx0; by1 = by0; bz1 = bz0; }
        for (int bx = bx0; bx <= bx1; ++bx)
            for (int by = by0; by <= by1; ++by)
                for (int bz = bz0; bz <= bz1; ++bz)
                    atomicAdd(&h[(bx << 6) + (by << 3) + bz], 1u);
    }
    __syncthreads();

    unsigned* dst = bcnt + (size_t)blk * nkeys + (size_t)cb * SBINS;
    for (int k = threadIdx.x; k < SBINS; k += 256) dst[k] = h[k];
    // zero the other slices' keys for this chunk row (they get no points)
    for (int k = threadIdx.x; k < nkeys - SBINS; k += 256) {
        int g = k + ((k >= cb * SBINS) ? SBINS : 0);
        bcnt[(size_t)blk * nkeys + g] = 0u;
    }
}

// ---------------- Pass 2a: per-key totals ----------------
__global__ __launch_bounds__(256) void keytotal_kernel(
    const unsigned* __restrict__ bcnt, unsigned* __restrict__ keytotal,
    int nkeys, int nblocks)
{
    int g = blockIdx.x * 256 + threadIdx.x;
    if (g >= nkeys) return;
    unsigned s = 0;
    for (int c = 0; c < nblocks; ++c) s += bcnt[(size_t)c * nkeys + g];
    keytotal[g] = s;
}

// ---------------- Pass 2b: exclusive scan over keys (1 block) ----------------
__global__ __launch_bounds__(1024) void scan_kernel(
    const unsigned* __restrict__ counts,
    unsigned* __restrict__ key_start,   // nkeys+1
    int nkeys)
{
    __shared__ unsigned part[1024];
    int tid = threadIdx.x;
    int chunk = (nkeys + 1023) / 1024;
    int lo = tid * chunk;
    unsigned s = 0;
    for (int i = 0; i < chunk; ++i) {
        int k = lo + i;
        if (k < nkeys) s += counts[k];
    }
    part[tid] = s;
    __syncthreads();
    for (int off = 1; off < 1024; off <<= 1) {
        unsigned v = (tid >= off) ? part[tid - off] : 0u;
        __syncthreads();
        part[tid] += v;
        __syncthreads();
    }
    unsigned run = (tid == 0) ? 0u : part[tid - 1];
    for (int i = 0; i < chunk; ++i) {
        int k = lo + i;
        if (k < nkeys) {
            key_start[k] = run;
            run += counts[k];
        }
    }
    if (tid == 1023) key_start[nkeys] = run;
}

// ---------------- Pass 2c: per-(key,chunk) starts ----------------
__global__ __launch_bounds__(256) void chunkstart_kernel(
    const unsigned* __restrict__ bcnt, const unsigned* __restrict__ keystart,
    unsigned* __restrict__ bstart, int nkeys, int nblocks)
{
    int g = blockIdx.x * 256 + threadIdx.x;
    if (g >= nkeys) return;
    unsigned run = keystart[g];
    for (int c = 0; c < nblocks; ++c) {
        size_t a = (size_t)c * nkeys + g;
        unsigned t = bcnt[a];
        bstart[a] = run;
        run += t;
    }
}

// ---------------- Pass 3: scatter via LDS cursors (no global atomics) -------
__global__ __launch_bounds__(256) void scatter2_kernel(
    const float* __restrict__ p0, const float* __restrict__ p1,
    const unsigned* __restrict__ bstart,
    float4* __restrict__ sorted, unsigned cap,
    int N, int B, int nchunks, int nkeys, int dup)
{
    __shared__ unsigned cur[SBINS];
    int blk = blockIdx.x;
    int cb = blk / nchunks;
    int c  = blk - cb * nchunks;
    const unsigned* src = bstart + (size_t)blk * nkeys + (size_t)cb * SBINS;
    for (int k = threadIdx.x; k < SBINS; k += 256) cur[k] = src[k];
    __syncthreads();

    const float* p = (cb < B ? p0 : p1) +
                     ((size_t)(cb % B) * N + (size_t)c * CHUNK) * 3;
    for (int i = threadIdx.x; i < CHUNK; i += 256) {
        float px = p[3*i+0] * 64.0f;
        float py = p[3*i+1] * 64.0f;
        float pz = p[3*i+2] * 64.0f;
        float lx = floorf(px), ly = floorf(py), lz = floorf(pz);
        int ix = (int)lx + 64, iy = (int)ly + 64, iz = (int)lz + 64;
        unsigned packed = (unsigned)ix | ((unsigned)iy << 8) | ((unsigned)iz << 16);
        float4 rec = make_float4(px - lx, py - ly, pz - lz, __uint_as_float(packed));
        int bx0 = ix >> 4, by0 = iy >> 4, bz0 = iz >> 4;
        int bx1 = (ix+1) >> 4, by1 = (iy+1) >> 4, bz1 = (iz+1) >> 4;
        if (!dup) { bx1 = bx0; by1 = by0; bz1 = bz0; }
        for (int bx = bx0; bx <= bx1; ++bx)
            for (int by = by0; by <= by1; ++by)
                for (int bz = bz0; bz <= bz1; ++bz) {
                    unsigned slot = atomicAdd(&cur[(bx << 6) + (by << 3) + bz], 1u);
                    if (slot < cap) sorted[slot] = rec;
                }
    }
}

// ---------------- Pass 4: per-region gather + LDS accumulate ----------------
__global__ __launch_bounds__(256) void gather2_kernel(
    const float4* __restrict__ sorted,
    const unsigned* __restrict__ keystart,
    const unsigned* __restrict__ keytotal,
    float* __restrict__ out, int dup)
{
    __shared__ float acc[BIN * BIN * BIN];  // 16 KB
    int g = blockIdx.x;
    int cb = g >> 9;
    int r = g & (SBINS - 1);
    int rx = r >> 6, ry = (r >> 3) & 7, rz = r & 7;
    int x0 = rx << 4, y0 = ry << 4, z0 = rz << 4;

    for (int i = threadIdx.x; i < BIN * BIN * BIN; i += 256) acc[i] = 0.0f;
    __syncthreads();

    int sxlo = dup ? rx : max(rx - 1, 0);
    int sylo = dup ? ry : max(ry - 1, 0);
    int szlo = dup ? rz : max(rz - 1, 0);
    int kb = cb * SBINS;
    for (int sx = sxlo; sx <= rx; ++sx)
        for (int sy = sylo; sy <= ry; ++sy)
            for (int sz = szlo; sz <= rz; ++sz) {
                int gk = kb + (sx << 6) + (sy << 3) + sz;
                unsigned s = keystart[gk], e = s + keytotal[gk];
                for (unsigned i = s + threadIdx.x; i < e; i += 256) {
                    float4 pt = sorted[i];
                    unsigned pk = __float_as_uint(pt.w);
                    int lx = (int)(pk & 0xff) - x0;
                    int ly = (int)((pk >> 8) & 0xff) - y0;
                    int lz = (int)((pk >> 16) & 0xff) - z0;
                    float gx[2] = {1.0f - pt.x, pt.x};
                    float gy[2] = {1.0f - pt.y, pt.y};
                    float gz[2] = {1.0f - pt.z, pt.z};
#pragma unroll
                    for (int dx = 0; dx < 2; ++dx) {
                        int cx = lx + dx;
                        if ((unsigned)cx >= (unsigned)BIN) continue;
#pragma unroll
                        for (int dy = 0; dy < 2; ++dy) {
                            int cy = ly + dy;
                            if ((unsigned)cy >= (unsigned)BIN) continue;
#pragma unroll
                            for (int dz = 0; dz < 2; ++dz) {
                                int cz = lz + dz;
                                if ((unsigned)cz >= (unsigned)BIN) continue;
                                atomicAdd(&acc[(cx * BIN + cy) * BIN + cz],
                                          gx[dx] * gy[dy] * gz[dz]);
                            }
                        }
                    }
                }
            }
    __syncthreads();

    float* ob = out + (size_t)cb * NVERT;
    int row = threadIdx.x;
    int lx = row >> 4, ly = row & 15;
    size_t o = (((size_t)(x0 + lx) * DXYZ) + (size_t)(y0 + ly)) * DXYZ + z0;
    float4* op = (float4*)(ob + o);
    const float4* ap = (const float4*)&acc[row * BIN];
    op[0] = ap[0]; op[1] = ap[1]; op[2] = ap[2]; op[3] = ap[3];
}

// ---------------- Fallback: direct atomic splat ----------------
__global__ __launch_bounds__(256) void splat_kernel(
    const float* __restrict__ pts, float* __restrict__ out,
    int n_per_batch, int total)
{
    int t = blockIdx.x * blockDim.x + threadIdx.x;
    if (t >= total) return;
    float px = pts[3*t+0] * 64.0f, py = pts[3*t+1] * 64.0f, pz = pts[3*t+2] * 64.0f;
    float lx = floorf(px), ly = floorf(py), lz = floorf(pz);
    float fx = px - lx, fy = py - ly, fz = pz - lz;
    int ix = (int)lx + 64, iy = (int)ly + 64, iz = (int)lz + 64;
    int b = t / n_per_batch;
    float* o = out + (size_t)b * NVERT;
    size_t base = ((size_t)ix * DXYZ + (size_t)iy) * DXYZ + (size_t)iz;
    float gx[2] = {1.0f-fx, fx}, gy[2] = {1.0f-fy, fy}, gz[2] = {1.0f-fz, fz};
#pragma unroll
    for (int dx = 0; dx < 2; ++dx)
#pragma unroll
        for (int dy = 0; dy < 2; ++dy)
#pragma unroll
            for (int dz = 0; dz < 2; ++dz)
                atomicAdd(o + base + (size_t)dx * (DXYZ*DXYZ) + dy * DXYZ + dz,
                          gx[dx] * gy[dy] * gz[dz]);
}

static inline size_t align256(size_t x) { return (x + 255) & ~(size_t)255; }

extern "C" void kernel_launch(void* const* d_in, const int* in_sizes, int n_in,
                              void* d_out, int out_size, void* d_ws, size_t ws_size,
                              hipStream_t stream) {
    const float* pred = (const float*)d_in[0];
    const float* gt   = (const float*)d_in[1];
    float* out = (float*)d_out;

    int total = in_sizes[0] / 3;           // B*N points per cloud
    int B = out_size / (2 * NVERT);
    int N = total / B;
    int CB = 2 * B;
    int nchunks = N / CHUNK;
    int nkeys = CB * SBINS;
    int nblocks = CB * nchunks;
    size_t points_all = (size_t)2 * total;
    bool divisible = (N % CHUNK) == 0 && N > 0;

    // Workspace layout
    size_t off_keytotal = 0;
    size_t off_keystart = align256((size_t)nkeys * 4);
    size_t off_bcnt     = off_keystart + align256(((size_t)nkeys + 1) * 4);
    size_t bcnt_bytes   = align256((size_t)nblocks * nkeys * 4);
    size_t off_bstart   = off_bcnt + bcnt_bytes;
    size_t off_sorted   = off_bstart + bcnt_bytes;
    size_t cap = (ws_size > off_sorted) ? (ws_size - off_sorted) / sizeof(float4) : 0;

    // dup path duplicates each point into every bin it touches (E[x] ~= 1.20);
    // 1.5x capacity is a >60-sigma margin for uniform inputs.
    bool can_dup   = divisible && cap >= points_all + points_all / 2;
    bool can_nodup = divisible && cap >= points_all;

    if (!can_nodup) {
        hipMemsetAsync(d_out, 0, (size_t)out_size * sizeof(float), stream);
        int blocks = (total + 255) / 256;
        splat_kernel<<<blocks, 256, 0, stream>>>(pred, out, N, total);
        splat_kernel<<<blocks, 256, 0, stream>>>(gt, out + (size_t)B * NVERT, N, total);
        return;
    }
    int dup = can_dup ? 1 : 0;

    char* ws = (char*)d_ws;
    unsigned* keytotal = (unsigned*)(ws + off_keytotal);
    unsigned* keystart = (unsigned*)(ws + off_keystart);
    unsigned* bcnt     = (unsigned*)(ws + off_bcnt);
    unsigned* bstart   = (unsigned*)(ws + off_bstart);
    float4*   sorted   = (float4*)(ws + off_sorted);

    hist2_kernel<<<nblocks, 256, 0, stream>>>(pred, gt, bcnt, N, B,
                                              nchunks, nkeys, dup);
    int kb = (nkeys + 255) / 256;
    keytotal_kernel<<<kb, 256, 0, stream>>>(bcnt, keytotal, nkeys, nblocks);
    scan_kernel<<<1, 1024, 0, stream>>>(keytotal, keystart, nkeys);
    chunkstart_kernel<<<kb, 256, 0, stream>>>(bcnt, keystart, bstart,
                                              nkeys, nblocks);
    scatter2_kernel<<<nblocks, 256, 0, stream>>>(pred, gt, bstart, sorted,
                                                 (unsigned)cap, N, B,
                                                 nchunks, nkeys, dup);
    gather2_kernel<<<nkeys, 256, 0, stream>>>(sorted, keystart, keytotal,
                                              out, dup);
}

// Round 4
// 231.002 us; speedup vs baseline: 3.0621x; 3.0621x over previous
//
#include <hip/hip_runtime.h>

#define DXYZ 128
#define NVERT (DXYZ * DXYZ * DXYZ)     // 2097152 voxels per (cloud,batch) grid
#define BIN 16                          // region/bin edge in voxels
#define SBINS 512                       // spatial bins per grid (8^3)
#define CHUNK 2048                      // points per hist/scatter block
#define MAXCHUNKS 1024                  // chunkscan LDS capacity

// ---------------- Pass 1: per-chunk LDS histogram ----------------
// bcnt layout: [key][chunk], key = cb*SBINS + sbin, chunk within slice.
__global__ __launch_bounds__(256) void hist2_kernel(
    const float* __restrict__ p0, const float* __restrict__ p1,
    unsigned* __restrict__ bcnt,
    int N, int B, int nchunks, int dup)
{
    __shared__ unsigned h[SBINS];
    for (int i = threadIdx.x; i < SBINS; i += 256) h[i] = 0u;
    __syncthreads();

    int blk = blockIdx.x;
    int cb = blk / nchunks;            // cloud*B + batch
    int c  = blk - cb * nchunks;       // chunk within slice
    const float* p = (cb < B ? p0 : p1) +
                     ((size_t)(cb % B) * N + (size_t)c * CHUNK) * 3;

    for (int i = threadIdx.x; i < CHUNK; i += 256) {
        float px = p[3*i+0] * 64.0f;
        float py = p[3*i+1] * 64.0f;
        float pz = p[3*i+2] * 64.0f;
        int ix = (int)floorf(px) + 64;
        int iy = (int)floorf(py) + 64;
        int iz = (int)floorf(pz) + 64;
        int bx0 = ix >> 4, by0 = iy >> 4, bz0 = iz >> 4;
        int bx1 = (ix+1) >> 4, by1 = (iy+1) >> 4, bz1 = (iz+1) >> 4;
        if (!dup) { bx1 = bx0; by1 = by0; bz1 = bz0; }
        for (int bx = bx0; bx <= bx1; ++bx)
            for (int by = by0; by <= by1; ++by)
                for (int bz = bz0; bz <= bz1; ++bz)
                    atomicAdd(&h[(bx << 6) + (by << 3) + bz], 1u);
    }
    __syncthreads();

    for (int k = threadIdx.x; k < SBINS; k += 256)
        bcnt[(size_t)(cb * SBINS + k) * nchunks + c] = h[k];
}

// ---------------- Pass 2a: per-key exclusive scan over chunks ----------------
// One block per key; Hillis-Steele over nchunks values in LDS.
__global__ __launch_bounds__(256) void chunkscan_kernel(
    const unsigned* __restrict__ bcnt,   // [key][chunk]
    unsigned* __restrict__ bscan,        // [key][chunk] exclusive within key
    unsigned* __restrict__ keytotal,     // [key]
    int nchunks)
{
    __shared__ unsigned s[MAXCHUNKS];
    int key = blockIdx.x;
    const unsigned* src = bcnt + (size_t)key * nchunks;
    unsigned* dst = bscan + (size_t)key * nchunks;

    for (int i = threadIdx.x; i < nchunks; i += 256) s[i] = src[i];
    __syncthreads();
    for (int off = 1; off < nchunks; off <<= 1) {
        unsigned v[MAXCHUNKS / 256];
        int nv = 0;
        for (int i = threadIdx.x; i < nchunks; i += 256)
            v[nv++] = (i >= off) ? s[i - off] : 0u;
        __syncthreads();
        nv = 0;
        for (int i = threadIdx.x; i < nchunks; i += 256)
            s[i] += v[nv++];
        __syncthreads();
    }
    for (int i = threadIdx.x; i < nchunks; i += 256)
        dst[i] = (i == 0) ? 0u : s[i - 1];
    if (threadIdx.x == 0) keytotal[key] = s[nchunks - 1];
}

// ---------------- Pass 2b: exclusive scan over keys (1 block) ----------------
__global__ __launch_bounds__(1024) void scan_kernel(
    const unsigned* __restrict__ counts,
    unsigned* __restrict__ key_start,   // nkeys+1
    int nkeys)
{
    __shared__ unsigned part[1024];
    int tid = threadIdx.x;
    int chunk = (nkeys + 1023) / 1024;
    int lo = tid * chunk;
    unsigned s = 0;
    for (int i = 0; i < chunk; ++i) {
        int k = lo + i;
        if (k < nkeys) s += counts[k];
    }
    part[tid] = s;
    __syncthreads();
    for (int off = 1; off < 1024; off <<= 1) {
        unsigned v = (tid >= off) ? part[tid - off] : 0u;
        __syncthreads();
        part[tid] += v;
        __syncthreads();
    }
    unsigned run = (tid == 0) ? 0u : part[tid - 1];
    for (int i = 0; i < chunk; ++i) {
        int k = lo + i;
        if (k < nkeys) {
            key_start[k] = run;
            run += counts[k];
        }
    }
    if (tid == 1023) key_start[nkeys] = run;
}

// ---------------- Pass 3: scatter via LDS cursors ----------------
__global__ __launch_bounds__(256) void scatter2_kernel(
    const float* __restrict__ p0, const float* __restrict__ p1,
    const unsigned* __restrict__ bscan,     // [key][chunk]
    const unsigned* __restrict__ keystart,  // [key]
    float4* __restrict__ sorted, unsigned cap,
    int N, int B, int nchunks, int dup)
{
    __shared__ unsigned cur[SBINS];
    int blk = blockIdx.x;
    int cb = blk / nchunks;
    int c  = blk - cb * nchunks;
    for (int k = threadIdx.x; k < SBINS; k += 256) {
        int key = cb * SBINS + k;
        cur[k] = keystart[key] + bscan[(size_t)key * nchunks + c];
    }
    __syncthreads();

    const float* p = (cb < B ? p0 : p1) +
                     ((size_t)(cb % B) * N + (size_t)c * CHUNK) * 3;
    for (int i = threadIdx.x; i < CHUNK; i += 256) {
        float px = p[3*i+0] * 64.0f;
        float py = p[3*i+1] * 64.0f;
        float pz = p[3*i+2] * 64.0f;
        float lx = floorf(px), ly = floorf(py), lz = floorf(pz);
        int ix = (int)lx + 64, iy = (int)ly + 64, iz = (int)lz + 64;
        unsigned packed = (unsigned)ix | ((unsigned)iy << 8) | ((unsigned)iz << 16);
        float4 rec = make_float4(px - lx, py - ly, pz - lz, __uint_as_float(packed));
        int bx0 = ix >> 4, by0 = iy >> 4, bz0 = iz >> 4;
        int bx1 = (ix+1) >> 4, by1 = (iy+1) >> 4, bz1 = (iz+1) >> 4;
        if (!dup) { bx1 = bx0; by1 = by0; bz1 = bz0; }
        for (int bx = bx0; bx <= bx1; ++bx)
            for (int by = by0; by <= by1; ++by)
                for (int bz = bz0; bz <= bz1; ++bz) {
                    unsigned slot = atomicAdd(&cur[(bx << 6) + (by << 3) + bz], 1u);
                    if (slot < cap) sorted[slot] = rec;
                }
    }
}

// ---------------- Pass 4: per-region gather + LDS accumulate ----------------
__global__ __launch_bounds__(256) void gather2_kernel(
    const float4* __restrict__ sorted,
    const unsigned* __restrict__ keystart,
    const unsigned* __restrict__ keytotal,
    float* __restrict__ out, int dup)
{
    __shared__ float acc[BIN * BIN * BIN];  // 16 KB
    int g = blockIdx.x;
    int cb = g >> 9;
    int r = g & (SBINS - 1);
    int rx = r >> 6, ry = (r >> 3) & 7, rz = r & 7;
    int x0 = rx << 4, y0 = ry << 4, z0 = rz << 4;

    for (int i = threadIdx.x; i < BIN * BIN * BIN; i += 256) acc[i] = 0.0f;
    __syncthreads();

    int sxlo = dup ? rx : max(rx - 1, 0);
    int sylo = dup ? ry : max(ry - 1, 0);
    int szlo = dup ? rz : max(rz - 1, 0);
    int kb = cb * SBINS;
    for (int sx = sxlo; sx <= rx; ++sx)
        for (int sy = sylo; sy <= ry; ++sy)
            for (int sz = szlo; sz <= rz; ++sz) {
                int gk = kb + (sx << 6) + (sy << 3) + sz;
                unsigned s = keystart[gk], e = s + keytotal[gk];
                for (unsigned i = s + threadIdx.x; i < e; i += 256) {
                    float4 pt = sorted[i];
                    unsigned pk = __float_as_uint(pt.w);
                    int lx = (int)(pk & 0xff) - x0;
                    int ly = (int)((pk >> 8) & 0xff) - y0;
                    int lz = (int)((pk >> 16) & 0xff) - z0;
                    float gx[2] = {1.0f - pt.x, pt.x};
                    float gy[2] = {1.0f - pt.y, pt.y};
                    float gz[2] = {1.0f - pt.z, pt.z};
#pragma unroll
                    for (int dx = 0; dx < 2; ++dx) {
                        int cx = lx + dx;
                        if ((unsigned)cx >= (unsigned)BIN) continue;
#pragma unroll
                        for (int dy = 0; dy < 2; ++dy) {
                            int cy = ly + dy;
                            if ((unsigned)cy >= (unsigned)BIN) continue;
#pragma unroll
                            for (int dz = 0; dz < 2; ++dz) {
                                int cz = lz + dz;
                                if ((unsigned)cz >= (unsigned)BIN) continue;
                                atomicAdd(&acc[(cx * BIN + cy) * BIN + cz],
                                          gx[dx] * gy[dy] * gz[dz]);
                            }
                        }
                    }
                }
            }
    __syncthreads();

    float* ob = out + (size_t)cb * NVERT;
    int row = threadIdx.x;
    int lx = row >> 4, ly = row & 15;
    size_t o = (((size_t)(x0 + lx) * DXYZ) + (size_t)(y0 + ly)) * DXYZ + z0;
    float4* op = (float4*)(ob + o);
    const float4* ap = (const float4*)&acc[row * BIN];
    op[0] = ap[0]; op[1] = ap[1]; op[2] = ap[2]; op[3] = ap[3];
}

// ---------------- Fallback: direct atomic splat ----------------
__global__ __launch_bounds__(256) void splat_kernel(
    const float* __restrict__ pts, float* __restrict__ out,
    int n_per_batch, int total)
{
    int t = blockIdx.x * blockDim.x + threadIdx.x;
    if (t >= total) return;
    float px = pts[3*t+0] * 64.0f, py = pts[3*t+1] * 64.0f, pz = pts[3*t+2] * 64.0f;
    float lx = floorf(px), ly = floorf(py), lz = floorf(pz);
    float fx = px - lx, fy = py - ly, fz = pz - lz;
    int ix = (int)lx + 64, iy = (int)ly + 64, iz = (int)lz + 64;
    int b = t / n_per_batch;
    float* o = out + (size_t)b * NVERT;
    size_t base = ((size_t)ix * DXYZ + (size_t)iy) * DXYZ + (size_t)iz;
    float gx[2] = {1.0f-fx, fx}, gy[2] = {1.0f-fy, fy}, gz[2] = {1.0f-fz, fz};
#pragma unroll
    for (int dx = 0; dx < 2; ++dx)
#pragma unroll
        for (int dy = 0; dy < 2; ++dy)
#pragma unroll
            for (int dz = 0; dz < 2; ++dz)
                atomicAdd(o + base + (size_t)dx * (DXYZ*DXYZ) + dy * DXYZ + dz,
                          gx[dx] * gy[dy] * gz[dz]);
}

static inline size_t align256(size_t x) { return (x + 255) & ~(size_t)255; }

extern "C" void kernel_launch(void* const* d_in, const int* in_sizes, int n_in,
                              void* d_out, int out_size, void* d_ws, size_t ws_size,
                              hipStream_t stream) {
    const float* pred = (const float*)d_in[0];
    const float* gt   = (const float*)d_in[1];
    float* out = (float*)d_out;

    int total = in_sizes[0] / 3;           // B*N points per cloud
    int B = out_size / (2 * NVERT);
    int N = total / B;
    int CB = 2 * B;
    int nchunks = N / CHUNK;
    int nkeys = CB * SBINS;
    int nblocks = CB * nchunks;
    size_t points_all = (size_t)2 * total;
    bool divisible = (N % CHUNK) == 0 && N > 0 && nchunks <= MAXCHUNKS;

    // Workspace layout
    size_t off_keytotal = 0;
    size_t off_keystart = align256((size_t)nkeys * 4);
    size_t off_bcnt     = off_keystart + align256(((size_t)nkeys + 1) * 4);
    size_t mat_bytes    = align256((size_t)nkeys * nchunks * 4);
    size_t off_bscan    = off_bcnt + mat_bytes;
    size_t off_sorted   = off_bscan + mat_bytes;
    size_t cap = (ws_size > off_sorted) ? (ws_size - off_sorted) / sizeof(float4) : 0;

    // dup path duplicates each point into every bin it touches (E[x] ~= 1.20);
    // 1.5x capacity is a >60-sigma margin for uniform inputs.
    bool can_dup   = divisible && cap >= points_all + points_all / 2;
    bool can_nodup = divisible && cap >= points_all;

    if (!can_nodup) {
        hipMemsetAsync(d_out, 0, (size_t)out_size * sizeof(float), stream);
        int blocks = (total + 255) / 256;
        splat_kernel<<<blocks, 256, 0, stream>>>(pred, out, N, total);
        splat_kernel<<<blocks, 256, 0, stream>>>(gt, out + (size_t)B * NVERT, N, total);
        return;
    }
    int dup = can_dup ? 1 : 0;

    char* ws = (char*)d_ws;
    unsigned* keytotal = (unsigned*)(ws + off_keytotal);
    unsigned* keystart = (unsigned*)(ws + off_keystart);
    unsigned* bcnt     = (unsigned*)(ws + off_bcnt);
    unsigned* bscan    = (unsigned*)(ws + off_bscan);
    float4*   sorted   = (float4*)(ws + off_sorted);

    hist2_kernel<<<nblocks, 256, 0, stream>>>(pred, gt, bcnt, N, B, nchunks, dup);
    chunkscan_kernel<<<nkeys, 256, 0, stream>>>(bcnt, bscan, keytotal, nchunks);
    scan_kernel<<<1, 1024, 0, stream>>>(keytotal, keystart, nkeys);
    scatter2_kernel<<<nblocks, 256, 0, stream>>>(pred, gt, bscan, keystart, sorted,
                                                 (unsigned)cap, N, B, nchunks, dup);
    gather2_kernel<<<nkeys, 256, 0, stream>>>(sorted, keystart, keytotal, out, dup);
}